// Round 2
// baseline (920.234 us; speedup 1.0000x reference)
//
#include <hip/hip_runtime.h>
#include <math.h>

#define B_TOTAL 2048
#define T_LEN   512
#define IN_D    6
#define HID     64
#define LAT     16
#define ROWS    2        // batch rows per block
#define THREADS 192      // 3 waves: wave g owns gate g (r/z/n), lane j = output unit

__device__ __forceinline__ float fast_sigmoid(float x){
    float e = __expf(-x);
    return __fdividef(1.0f, 1.0f + e);
}
__device__ __forceinline__ float fast_tanh(float x){
    float e = __expf(2.0f * x);                 // inf for large x is fine: 2/inf -> 0
    return 1.0f - __fdividef(2.0f, e + 1.0f);
}

// Layout: lane (g, j) owns Whh row g*64+j (64 floats, 16 VGPR float4s) and
// Wih row g*64+j (6 floats). Per step it computes the full k=64 dot product
// for ROWS batch rows via wave-uniform LDS broadcast reads of h — NO
// cross-lane reduction, NO shuffles. Gate combine via presh + 2 barriers.
extern "C" __global__ __launch_bounds__(THREADS, 3)
void glsde_kernel(const float* __restrict__ x,
                  const float* __restrict__ eWih, const float* __restrict__ eWhh,
                  const float* __restrict__ ebih, const float* __restrict__ ebhh,
                  const float* __restrict__ muW,  const float* __restrict__ mub,
                  const float* __restrict__ lvW,  const float* __restrict__ lvb,
                  const float* __restrict__ oW,   const float* __restrict__ ob,
                  const float* __restrict__ dfW,  const float* __restrict__ dfb,
                  const float* __restrict__ dWih, const float* __restrict__ dWhh,
                  const float* __restrict__ dbih, const float* __restrict__ dbhh,
                  float* __restrict__ out)
{
    __shared__ float hsh[ROWS][HID];         // hidden state (single buffer: only owner lane rewrites)
    __shared__ float presh[ROWS][4][HID];    // pre-activations: r, z, n_x, n_h  ([r][gate][j]: stride-1 in j -> conflict-free)
    __shared__ float xsh[2][ROWS][IN_D];     // double-buffered x(t)
    __shared__ float zsh[ROWS][LAT];
    __shared__ float zdsh[ROWS][HID];
    __shared__ float xgdsh[ROWS][3];
    __shared__ float outsh[ROWS][T_LEN];

    const int tid = threadIdx.x;
    const int g   = tid >> 6;       // wave: 0=r, 1=z, 2=n
    const int j   = tid & 63;       // output unit
    const int b0  = blockIdx.x * ROWS;

    // ---- stationary weights -> registers ----
    float4 W4[16];                  // Whh[g*64+j][0..63]
    {
        const float4* wp = (const float4*)(eWhh + (size_t)(g * HID + j) * HID);
        #pragma unroll
        for (int q = 0; q < 16; ++q) W4[q] = wp[q];
    }
    float wx[IN_D];                 // Wih[g*64+j][0..5]
    #pragma unroll
    for (int d = 0; d < IN_D; ++d) wx[d] = eWih[(size_t)(g * HID + j) * IN_D + d];
    float bias0, bias1 = 0.0f;
    if (g < 2) bias0 = ebih[g * HID + j] + ebhh[g * HID + j];
    else { bias0 = ebih[2 * HID + j]; bias1 = ebhh[2 * HID + j]; }  // bihn, bhhn

    // ---- init h=0, x(t=0); prefetch lanes live in wave 2 ----
    if (tid < ROWS * HID) hsh[tid >> 6][tid & 63] = 0.0f;
    const int pl = tid - 2 * HID;                    // 0..63 in wave 2
    int xrow = 0, xd = 0;
    const float* xptr = nullptr;
    if (pl >= 0 && pl < ROWS * IN_D){
        xrow = pl / IN_D; xd = pl % IN_D;
        xptr = x + (size_t)(b0 + xrow) * T_LEN * IN_D + xd;
        xsh[0][xrow][xd] = xptr[0];
    }
    __syncthreads();

    // ================= encoder GRU: 512 sequential steps =================
    int cb = 0;
    for (int t = 0; t < T_LEN; ++t){
        // prefetch x(t+1) (global latency hidden under the FMA block)
        float xpre = 0.0f;
        if (pl >= 0 && pl < ROWS * IN_D){
            int tn = (t + 1 < T_LEN) ? (t + 1) : (T_LEN - 1);
            xpre = xptr[(size_t)tn * IN_D];
        }

        // full-k dot products, 2 independent partial chains per row for ILP
        float a0a = 0.f, a0b = 0.f, a1a = 0.f, a1b = 0.f;
        const float4* h0 = (const float4*)(&hsh[0][0]);   // wave-uniform -> broadcast
        const float4* h1 = (const float4*)(&hsh[1][0]);
        #pragma unroll
        for (int q = 0; q < 8; ++q){
            float4 w1 = W4[q], w2 = W4[q + 8];
            float4 p0 = h0[q], p1 = h0[q + 8];
            float4 p2 = h1[q], p3 = h1[q + 8];
            a0a += w1.x*p0.x + w1.y*p0.y + w1.z*p0.z + w1.w*p0.w;
            a0b += w2.x*p1.x + w2.y*p1.y + w2.z*p1.z + w2.w*p1.w;
            a1a += w1.x*p2.x + w1.y*p2.y + w1.z*p2.z + w1.w*p2.w;
            a1b += w2.x*p3.x + w2.y*p3.y + w2.z*p3.z + w2.w*p3.w;
        }
        float acch0 = a0a + a0b, acch1 = a1a + a1b;
        float accx0 = 0.f, accx1 = 0.f;
        #pragma unroll
        for (int d = 0; d < IN_D; ++d){
            accx0 += wx[d] * xsh[cb][0][d];
            accx1 += wx[d] * xsh[cb][1][d];
        }
        if (g < 2){                                   // wave-uniform branch
            presh[0][g][j] = acch0 + accx0 + bias0;
            presh[1][g][j] = acch1 + accx1 + bias0;
        } else {
            presh[0][2][j] = accx0 + bias0;           // x-part + bihn
            presh[0][3][j] = acch0 + bias1;           // h-part + bhhn
            presh[1][2][j] = accx1 + bias0;
            presh[1][3][j] = acch1 + bias1;
        }
        __syncthreads();

        if (tid < ROWS * HID){                        // waves 0,1 finalize (row = g)
            const int r = g;
            float pr = presh[r][0][j], pz = presh[r][1][j];
            float px = presh[r][2][j], ph = presh[r][3][j];
            float rg = fast_sigmoid(pr);
            float zg = fast_sigmoid(pz);
            float ng = fast_tanh(px + rg * ph);
            hsh[r][j] = (1.0f - zg) * ng + zg * hsh[r][j];
        } else if (pl < ROWS * IN_D){                 // wave 2: commit x prefetch
            xsh[cb ^ 1][xrow][xd] = xpre;
        }
        __syncthreads();
        cb ^= 1;
    }

    // ================= heads: mu, logvar, z0 =================
    const int zrow = tid >> 4, zi = tid & 15;
    float z0v = 0.0f;
    if (tid < ROWS * LAT){
        float am = mub[zi], al = lvb[zi];
        const float4* pm = (const float4*)(muW + (size_t)zi * HID);
        const float4* pq = (const float4*)(lvW + (size_t)zi * HID);
        const float4* ph = (const float4*)(&hsh[zrow][0]);
        #pragma unroll
        for (int q = 0; q < 16; ++q){
            float4 wm = pm[q], wl = pq[q], hv = ph[q];
            am += wm.x*hv.x + wm.y*hv.y + wm.z*hv.z + wm.w*hv.w;
            al += wl.x*hv.x + wl.y*hv.y + wl.z*hv.z + wl.w*hv.w;
        }
        const size_t muBase = (size_t)B_TOTAL * T_LEN;
        out[muBase + (size_t)(b0 + zrow) * LAT + zi] = am;
        out[muBase + (size_t)B_TOTAL * LAT + (size_t)(b0 + zrow) * LAT + zi] = al;
        z0v = am + __expf(0.5f * al);   // z0 = mu + sqrt(exp(log_var))
    }

    // ================= ODE: RK4, 24 fixed steps on t in [0,1] =================
    if (tid < ROWS * LAT){
        float ows[16];
        {
            const float4* pw = (const float4*)(oW + (size_t)zi * LAT);
            #pragma unroll
            for (int q = 0; q < 4; ++q){
                float4 w = pw[q];
                ows[4*q+0] = w.x; ows[4*q+1] = w.y; ows[4*q+2] = w.z; ows[4*q+3] = w.w;
            }
        }
        const float obv = ob[zi];
        float z = z0v;
        const float hstep = 1.0f / 24.0f;
        for (int s = 0; s < 24; ++s){
            float y, k1, k2, k3, k4;
            y = z;
            { float acc = obv;
              #pragma unroll
              for (int jj = 0; jj < 16; ++jj){ float yj = __shfl(y, jj, 16); acc = fmaf(ows[jj], yj, acc); }
              k1 = fmaxf(acc, 0.0f); }
            y = z + 0.5f * hstep * k1;
            { float acc = obv;
              #pragma unroll
              for (int jj = 0; jj < 16; ++jj){ float yj = __shfl(y, jj, 16); acc = fmaf(ows[jj], yj, acc); }
              k2 = fmaxf(acc, 0.0f); }
            y = z + 0.5f * hstep * k2;
            { float acc = obv;
              #pragma unroll
              for (int jj = 0; jj < 16; ++jj){ float yj = __shfl(y, jj, 16); acc = fmaf(ows[jj], yj, acc); }
              k3 = fmaxf(acc, 0.0f); }
            y = z + hstep * k3;
            { float acc = obv;
              #pragma unroll
              for (int jj = 0; jj < 16; ++jj){ float yj = __shfl(y, jj, 16); acc = fmaf(ows[jj], yj, acc); }
              k4 = fmaxf(acc, 0.0f); }
            z += (hstep / 6.0f) * (k1 + 2.0f*k2 + 2.0f*k3 + k4);
        }
        zsh[zrow][zi] = z;
    }
    __syncthreads();

    // ================= decoder fc: zd = relu(z @ dfW.T + dfb) =================
    if (tid < ROWS * HID){
        const int row = tid >> 6, o = tid & 63;
        float acc = dfb[o];
        const float4* pw = (const float4*)(dfW + (size_t)o * LAT);
        const float4* pz = (const float4*)(&zsh[row][0]);
        #pragma unroll
        for (int q = 0; q < 4; ++q){
            float4 w = pw[q], zv = pz[q];
            acc += w.x*zv.x + w.y*zv.y + w.z*zv.z + w.w*zv.w;
        }
        zdsh[row][o] = fmaxf(acc, 0.0f);
    }
    __syncthreads();

    // xg_dec = zd @ dec_Wih.T + dec_bih   (3 gates per row, constant over time)
    if (tid < ROWS * 3){
        int row = tid / 3, gg = tid % 3;
        float acc = dbih[gg];
        const float4* pw = (const float4*)(dWih + (size_t)gg * HID);
        const float4* pz = (const float4*)(&zdsh[row][0]);
        #pragma unroll
        for (int q = 0; q < 16; ++q){
            float4 w = pw[q], zv = pz[q];
            acc += w.x*zv.x + w.y*zv.y + w.z*zv.z + w.w*zv.w;
        }
        xgdsh[row][gg] = acc;
    }
    __syncthreads();

    // ================= decoder GRU (hidden dim 1), 512 steps =================
    if (tid < ROWS){
        const int row = tid;
        const float xr = xgdsh[row][0], xz = xgdsh[row][1], xn = xgdsh[row][2];
        const float A0 = dWhh[0], A1 = dWhh[1], A2 = dWhh[2];
        const float c0 = dbhh[0], c1 = dbhh[1], c2 = dbhh[2];
        float h = 0.0f;
        for (int t = 0; t < T_LEN; ++t){
            float rr = fast_sigmoid(xr + A0 * h + c0);
            float zz = fast_sigmoid(xz + A1 * h + c1);
            float nn = fast_tanh(xn + rr * (A2 * h + c2));
            h = (1.0f - zz) * nn + zz * h;
            outsh[row][t] = h;
        }
    }
    __syncthreads();

    // coalesced write: rows b0, b0+1 are contiguous in out
    {
        const float4* ps = (const float4*)(&outsh[0][0]);
        float4* pd = (float4*)out;
        const size_t base4 = ((size_t)b0 * T_LEN) >> 2;
        for (int q = tid; q < (ROWS * T_LEN) / 4; q += THREADS)
            pd[base4 + q] = ps[q];
    }
}

extern "C" void kernel_launch(void* const* d_in, const int* in_sizes, int n_in,
                              void* d_out, int out_size, void* d_ws, size_t ws_size,
                              hipStream_t stream){
    glsde_kernel<<<B_TOTAL / ROWS, THREADS, 0, stream>>>(
        (const float*)d_in[0],  (const float*)d_in[1],  (const float*)d_in[2],
        (const float*)d_in[3],  (const float*)d_in[4],  (const float*)d_in[5],
        (const float*)d_in[6],  (const float*)d_in[7],  (const float*)d_in[8],
        (const float*)d_in[9],  (const float*)d_in[10], (const float*)d_in[11],
        (const float*)d_in[12], (const float*)d_in[13], (const float*)d_in[14],
        (const float*)d_in[15], (const float*)d_in[16], (float*)d_out);
}

// Round 3
// 629.199 us; speedup vs baseline: 1.4625x; 1.4625x over previous
//
#include <hip/hip_runtime.h>
#include <math.h>

#define B_TOTAL 2048
#define T_LEN   512
#define IN_D    6
#define HID     64
#define LAT     16
#define ROWS    8          // batch rows per block (M-tile 16, rows 8..15 zero)
#define THREADS 256        // 4 waves; wave w owns output units j in [16w, 16w+16)
#define KPAD    96         // A cols: h(64) | x(6) | zero pad -> 3 K-tiles of 32
#define ASTRIDE 104        // row stride (elems): 104*2B=208B=52 dwords, breaks bank aliasing

typedef __attribute__((ext_vector_type(8))) short bfrag;   // 8 bf16 = 4 VGPRs
typedef __attribute__((ext_vector_type(4))) float ffrag;   // 4 fp32 acc

__device__ __forceinline__ float fast_sigmoid(float x){
    float e = __expf(-x);
    return __fdividef(1.0f, 1.0f + e);
}
__device__ __forceinline__ float fast_tanh(float x){
    float e = __expf(2.0f * x);
    return 1.0f - __fdividef(2.0f, e + 1.0f);
}
__device__ __forceinline__ unsigned short f2bf_rne(float f){
    union { float f; unsigned u; } v; v.f = f;
    unsigned u = v.u;
    return (unsigned short)((u + 0x7fffu + ((u >> 16) & 1u)) >> 16);
}
__device__ __forceinline__ float bf2f(unsigned short b){
    union { unsigned u; float f; } v; v.u = ((unsigned)b) << 16;
    return v.f;
}

extern "C" __global__ void
__attribute__((amdgpu_flat_work_group_size(THREADS, THREADS), amdgpu_waves_per_eu(1, 1)))
glsde_kernel(const float* __restrict__ x,
             const float* __restrict__ eWih, const float* __restrict__ eWhh,
             const float* __restrict__ ebih, const float* __restrict__ ebhh,
             const float* __restrict__ muW,  const float* __restrict__ mub,
             const float* __restrict__ lvW,  const float* __restrict__ lvb,
             const float* __restrict__ oW,   const float* __restrict__ ob,
             const float* __restrict__ dfW,  const float* __restrict__ dfb,
             const float* __restrict__ dWih, const float* __restrict__ dWhh,
             const float* __restrict__ dbih, const float* __restrict__ dbhh,
             float* __restrict__ out)
{
    // [buf][hi=0/lo=1][m 0..15][k 0..95 (+pad)] bf16 bits
    __shared__ __align__(16) unsigned short Abuf[2][2][16][ASTRIDE];
    __shared__ float hfp[ROWS][HID];
    __shared__ float zsh[ROWS][LAT];
    __shared__ float zdsh[ROWS][HID];
    __shared__ float xgdsh[ROWS][3];
    __shared__ float outsh[ROWS][T_LEN];

    const int tid  = threadIdx.x;
    const int wave = tid >> 6;
    const int lane = tid & 63;
    const int nloc = lane & 15;       // B col within tile / D col
    const int quad = lane >> 4;       // 0..3
    const int mA   = lane & 15;       // A row this lane feeds
    const int j    = wave * 16 + nloc; // output unit 0..63 owned by this lane
    const int b0   = blockIdx.x * ROWS;

    // ---- B (weights) -> registers, hi/lo bf16 split, loaded ONCE ----
    // B[k][n]: lane holds k = 32*kt + quad*8 + e, n = gate-row. Gate rows:
    // r: j, z: 64+j, n_h: 128+j (Whh), n_x: 128+j (Wih, lives in k-tile 2)
    bfrag BrH[3], BrL[3], BzH[3], BzL[3], BnhH[2], BnhL[2], BnxH, BnxL;
    {
        const float* wr = eWhh + (size_t)(      j) * HID;
        const float* wz = eWhh + (size_t)( 64 + j) * HID;
        const float* wn = eWhh + (size_t)(128 + j) * HID;
        #pragma unroll
        for (int kt = 0; kt < 2; ++kt){
            const int o = kt * 32 + quad * 8;
            #pragma unroll
            for (int e = 0; e < 8; ++e){
                float a = wr[o + e], b = wz[o + e], c = wn[o + e];
                unsigned short ah = f2bf_rne(a), bh = f2bf_rne(b), ch = f2bf_rne(c);
                BrH[kt][e] = (short)ah; BrL[kt][e] = (short)f2bf_rne(a - bf2f(ah));
                BzH[kt][e] = (short)bh; BzL[kt][e] = (short)f2bf_rne(b - bf2f(bh));
                BnhH[kt][e] = (short)ch; BnhL[kt][e] = (short)f2bf_rne(c - bf2f(ch));
            }
        }
        const float* ir = eWih + (size_t)(      j) * IN_D;
        const float* iz = eWih + (size_t)( 64 + j) * IN_D;
        const float* in_ = eWih + (size_t)(128 + j) * IN_D;
        #pragma unroll
        for (int e = 0; e < 8; ++e){
            float a = (quad == 0 && e < IN_D) ? ir[e]  : 0.0f;
            float b = (quad == 0 && e < IN_D) ? iz[e]  : 0.0f;
            float c = (quad == 0 && e < IN_D) ? in_[e] : 0.0f;
            unsigned short ah = f2bf_rne(a), bh = f2bf_rne(b), ch = f2bf_rne(c);
            BrH[2][e] = (short)ah; BrL[2][e] = (short)f2bf_rne(a - bf2f(ah));
            BzH[2][e] = (short)bh; BzL[2][e] = (short)f2bf_rne(b - bf2f(bh));
            BnxH[e]   = (short)ch; BnxL[e]   = (short)f2bf_rne(c - bf2f(ch));
        }
    }
    const float bias_r = ebih[j]        + ebhh[j];
    const float bias_z = ebih[64 + j]   + ebhh[64 + j];
    const float bihn   = ebih[128 + j];
    const float bhhn   = ebhh[128 + j];

    // ---- zero A buffers (h(0)=0, pad rows/cols stay 0 forever) ----
    {
        unsigned* az = (unsigned*)Abuf;
        const int nW = (int)(sizeof(Abuf) / 4);
        for (int i = tid; i < nW; i += THREADS) az[i] = 0u;
    }
    __syncthreads();
    // ---- x(0) into buf 0 ----
    const int xm = tid / IN_D, xd = tid % IN_D;   // valid for tid < 48
    const float* xp = x + (size_t)(b0 + ((tid < ROWS * IN_D) ? xm : 0)) * T_LEN * IN_D
                        + ((tid < ROWS * IN_D) ? xd : 0);
    if (tid < ROWS * IN_D){
        float xv0 = xp[0];
        unsigned short hi = f2bf_rne(xv0);
        Abuf[0][0][xm][64 + xd] = hi;
        Abuf[0][1][xm][64 + xd] = f2bf_rne(xv0 - bf2f(hi));
    }
    __syncthreads();

    // fp32 h state lives in the lane that computes it: (m = quad*4+r, j)
    float hreg[4] = {0.f, 0.f, 0.f, 0.f};

    // ================= encoder GRU: 512 steps, 1 barrier/step =================
    int cb = 0;
    for (int t = 0; t < T_LEN; ++t){
        float xv = 0.0f;
        if (tid < ROWS * IN_D){
            int tn = (t + 1 < T_LEN) ? (t + 1) : (T_LEN - 1);
            xv = xp[(size_t)tn * IN_D];
        }

        // A fragments: lane reads row mA, k = 32*kt + quad*8 .. +8
        bfrag Ah[3], Al[3];
        {
            const unsigned short* ah = &Abuf[cb][0][mA][0];
            const unsigned short* al = &Abuf[cb][1][mA][0];
            #pragma unroll
            for (int kt = 0; kt < 3; ++kt){
                Ah[kt] = *(const bfrag*)(ah + kt * 32 + quad * 8);
                Al[kt] = *(const bfrag*)(al + kt * 32 + quad * 8);
            }
        }

        ffrag aR  = {0.f,0.f,0.f,0.f}, aZ = {0.f,0.f,0.f,0.f};
        ffrag aNH = {0.f,0.f,0.f,0.f}, aNX = {0.f,0.f,0.f,0.f};
        #pragma unroll
        for (int kt = 0; kt < 2; ++kt){
            aR  = __builtin_amdgcn_mfma_f32_16x16x32_bf16(Ah[kt], BrH[kt],  aR,  0,0,0);
            aZ  = __builtin_amdgcn_mfma_f32_16x16x32_bf16(Ah[kt], BzH[kt],  aZ,  0,0,0);
            aNH = __builtin_amdgcn_mfma_f32_16x16x32_bf16(Ah[kt], BnhH[kt], aNH, 0,0,0);
            aR  = __builtin_amdgcn_mfma_f32_16x16x32_bf16(Ah[kt], BrL[kt],  aR,  0,0,0);
            aZ  = __builtin_amdgcn_mfma_f32_16x16x32_bf16(Ah[kt], BzL[kt],  aZ,  0,0,0);
            aNH = __builtin_amdgcn_mfma_f32_16x16x32_bf16(Ah[kt], BnhL[kt], aNH, 0,0,0);
            aR  = __builtin_amdgcn_mfma_f32_16x16x32_bf16(Al[kt], BrH[kt],  aR,  0,0,0);
            aZ  = __builtin_amdgcn_mfma_f32_16x16x32_bf16(Al[kt], BzH[kt],  aZ,  0,0,0);
            aNH = __builtin_amdgcn_mfma_f32_16x16x32_bf16(Al[kt], BnhH[kt], aNH, 0,0,0);
        }
        aR  = __builtin_amdgcn_mfma_f32_16x16x32_bf16(Ah[2], BrH[2], aR,  0,0,0);
        aZ  = __builtin_amdgcn_mfma_f32_16x16x32_bf16(Ah[2], BzH[2], aZ,  0,0,0);
        aNX = __builtin_amdgcn_mfma_f32_16x16x32_bf16(Ah[2], BnxH,   aNX, 0,0,0);
        aR  = __builtin_amdgcn_mfma_f32_16x16x32_bf16(Ah[2], BrL[2], aR,  0,0,0);
        aZ  = __builtin_amdgcn_mfma_f32_16x16x32_bf16(Ah[2], BzL[2], aZ,  0,0,0);
        aNX = __builtin_amdgcn_mfma_f32_16x16x32_bf16(Ah[2], BnxL,   aNX, 0,0,0);
        aR  = __builtin_amdgcn_mfma_f32_16x16x32_bf16(Al[2], BrH[2], aR,  0,0,0);
        aZ  = __builtin_amdgcn_mfma_f32_16x16x32_bf16(Al[2], BzH[2], aZ,  0,0,0);
        aNX = __builtin_amdgcn_mfma_f32_16x16x32_bf16(Al[2], BnxH,   aNX, 0,0,0);

        // finalize: D row m = quad*4 + r, col = j. Valid m<8 <=> lane<32.
        float hnew[4];
        #pragma unroll
        for (int r = 0; r < 4; ++r){
            float rg = fast_sigmoid(aR[r] + bias_r);
            float zg = fast_sigmoid(aZ[r] + bias_z);
            float ng = fast_tanh(aNX[r] + bihn + rg * (aNH[r] + bhhn));
            hnew[r] = (1.0f - zg) * ng + zg * hreg[r];
            hreg[r] = hnew[r];
        }
        const int nb = cb ^ 1;
        if (lane < 32){
            #pragma unroll
            for (int r = 0; r < 4; ++r){
                unsigned short hi = f2bf_rne(hnew[r]);
                const int m = quad * 4 + r;
                Abuf[nb][0][m][j] = hi;
                Abuf[nb][1][m][j] = f2bf_rne(hnew[r] - bf2f(hi));
            }
        }
        if (tid < ROWS * IN_D){
            unsigned short hi = f2bf_rne(xv);
            Abuf[nb][0][xm][64 + xd] = hi;
            Abuf[nb][1][xm][64 + xd] = f2bf_rne(xv - bf2f(hi));
        }
        __syncthreads();
        cb = nb;
    }

    // ---- publish final h (fp32, from registers) ----
    if (lane < 32){
        #pragma unroll
        for (int r = 0; r < 4; ++r) hfp[quad * 4 + r][j] = hreg[r];
    }
    __syncthreads();

    // ================= heads: mu, logvar, z0 =================
    const int zrow = tid >> 4, zi = tid & 15;
    float z0v = 0.0f;
    if (tid < ROWS * LAT){
        float am = mub[zi], al = lvb[zi];
        const float4* pm = (const float4*)(muW + (size_t)zi * HID);
        const float4* pq = (const float4*)(lvW + (size_t)zi * HID);
        const float4* ph = (const float4*)(&hfp[zrow][0]);
        #pragma unroll
        for (int q = 0; q < 16; ++q){
            float4 wm = pm[q], wl = pq[q], hv = ph[q];
            am += wm.x*hv.x + wm.y*hv.y + wm.z*hv.z + wm.w*hv.w;
            al += wl.x*hv.x + wl.y*hv.y + wl.z*hv.z + wl.w*hv.w;
        }
        const size_t muBase = (size_t)B_TOTAL * T_LEN;
        out[muBase + (size_t)(b0 + zrow) * LAT + zi] = am;
        out[muBase + (size_t)B_TOTAL * LAT + (size_t)(b0 + zrow) * LAT + zi] = al;
        z0v = am + __expf(0.5f * al);
    }

    // ================= ODE: RK4, 24 fixed steps on [0,1] =================
    if (tid < ROWS * LAT){
        float ows[16];
        {
            const float4* pw = (const float4*)(oW + (size_t)zi * LAT);
            #pragma unroll
            for (int q = 0; q < 4; ++q){
                float4 w = pw[q];
                ows[4*q+0] = w.x; ows[4*q+1] = w.y; ows[4*q+2] = w.z; ows[4*q+3] = w.w;
            }
        }
        const float obv = ob[zi];
        float z = z0v;
        const float hstep = 1.0f / 24.0f;
        for (int s = 0; s < 24; ++s){
            float y, k1, k2, k3, k4;
            y = z;
            { float acc = obv;
              #pragma unroll
              for (int jj = 0; jj < 16; ++jj){ float yj = __shfl(y, jj, 16); acc = fmaf(ows[jj], yj, acc); }
              k1 = fmaxf(acc, 0.0f); }
            y = z + 0.5f * hstep * k1;
            { float acc = obv;
              #pragma unroll
              for (int jj = 0; jj < 16; ++jj){ float yj = __shfl(y, jj, 16); acc = fmaf(ows[jj], yj, acc); }
              k2 = fmaxf(acc, 0.0f); }
            y = z + 0.5f * hstep * k2;
            { float acc = obv;
              #pragma unroll
              for (int jj = 0; jj < 16; ++jj){ float yj = __shfl(y, jj, 16); acc = fmaf(ows[jj], yj, acc); }
              k3 = fmaxf(acc, 0.0f); }
            y = z + hstep * k3;
            { float acc = obv;
              #pragma unroll
              for (int jj = 0; jj < 16; ++jj){ float yj = __shfl(y, jj, 16); acc = fmaf(ows[jj], yj, acc); }
              k4 = fmaxf(acc, 0.0f); }
            z += (hstep / 6.0f) * (k1 + 2.0f*k2 + 2.0f*k3 + k4);
        }
        zsh[zrow][zi] = z;
    }
    __syncthreads();

    // ================= decoder fc: zd = relu(z @ dfW.T + dfb) =================
    for (int idx = tid; idx < ROWS * HID; idx += THREADS){
        const int row = idx >> 6, o = idx & 63;
        float acc = dfb[o];
        const float4* pw = (const float4*)(dfW + (size_t)o * LAT);
        const float4* pz = (const float4*)(&zsh[row][0]);
        #pragma unroll
        for (int q = 0; q < 4; ++q){
            float4 w = pw[q], zv = pz[q];
            acc += w.x*zv.x + w.y*zv.y + w.z*zv.z + w.w*zv.w;
        }
        zdsh[row][o] = fmaxf(acc, 0.0f);
    }
    __syncthreads();

    // xg_dec = zd @ dec_Wih.T + dec_bih
    if (tid < ROWS * 3){
        const int row = tid / 3, gg = tid % 3;
        float acc = dbih[gg];
        const float4* pw = (const float4*)(dWih + (size_t)gg * HID);
        const float4* pz = (const float4*)(&zdsh[row][0]);
        #pragma unroll
        for (int q = 0; q < 16; ++q){
            float4 w = pw[q], zv = pz[q];
            acc += w.x*zv.x + w.y*zv.y + w.z*zv.z + w.w*zv.w;
        }
        xgdsh[row][gg] = acc;
    }
    __syncthreads();

    // ================= decoder GRU (hidden dim 1), 512 steps =================
    if (tid < ROWS){
        const int row = tid;
        const float xr = xgdsh[row][0], xz = xgdsh[row][1], xn = xgdsh[row][2];
        const float A0 = dWhh[0], A1 = dWhh[1], A2 = dWhh[2];
        const float c0 = dbhh[0], c1 = dbhh[1], c2 = dbhh[2];
        float h = 0.0f;
        for (int t = 0; t < T_LEN; ++t){
            float rr = fast_sigmoid(xr + A0 * h + c0);
            float zz = fast_sigmoid(xz + A1 * h + c1);
            float nn = fast_tanh(xn + rr * (A2 * h + c2));
            h = (1.0f - zz) * nn + zz * h;
            outsh[row][t] = h;
        }
    }
    __syncthreads();

    // coalesced x_recon write: rows b0..b0+7 contiguous
    {
        const float4* ps = (const float4*)(&outsh[0][0]);
        float4* pd = (float4*)out;
        const size_t base4 = ((size_t)b0 * T_LEN) >> 2;
        for (int q = tid; q < (ROWS * T_LEN) / 4; q += THREADS)
            pd[base4 + q] = ps[q];
    }
}

extern "C" void kernel_launch(void* const* d_in, const int* in_sizes, int n_in,
                              void* d_out, int out_size, void* d_ws, size_t ws_size,
                              hipStream_t stream){
    glsde_kernel<<<B_TOTAL / ROWS, THREADS, 0, stream>>>(
        (const float*)d_in[0],  (const float*)d_in[1],  (const float*)d_in[2],
        (const float*)d_in[3],  (const float*)d_in[4],  (const float*)d_in[5],
        (const float*)d_in[6],  (const float*)d_in[7],  (const float*)d_in[8],
        (const float*)d_in[9],  (const float*)d_in[10], (const float*)d_in[11],
        (const float*)d_in[12], (const float*)d_in[13], (const float*)d_in[14],
        (const float*)d_in[15], (const float*)d_in[16], (float*)d_out);
}